// Round 1
// 487.367 us; speedup vs baseline: 1.0208x; 1.0208x over previous
//
#include <hip/hip_runtime.h>
#include <hip/hip_bf16.h>
#include <cstdint>
#include <cstddef>

// Problem constants (T5 self-attention, B=2, S=2048, H=16, D=64, d_model=1024)
#define S_LEN 2048
#define NH 16
#define DKV 64
#define BATCH 2
#define DMODEL 1024
#define LOG2E 1.4426950408889634f

typedef _Float16 half_t;
typedef __attribute__((ext_vector_type(4))) _Float16 halfx4;  // 8 B (also 16x16x16 A/B frag)
typedef __attribute__((ext_vector_type(8))) _Float16 half8;   // 16x16x32 A/B frag (4 VGPRs)
typedef __attribute__((ext_vector_type(4))) float floatx4;    // MFMA C/D frag

// async global->LDS, 16 B per lane; LDS dest = wave-uniform base + lane*16
__device__ __forceinline__ void load_lds16(const half_t* g, half_t* l) {
  __builtin_amdgcn_global_load_lds((const __attribute__((address_space(1))) void*)g,
                                   (__attribute__((address_space(3))) void*)l, 16, 0, 0);
}

// ---------------------------------------------------------------------------
// T5 relative-position bucket — EXACT integer thresholds (ceil(8*16^(n/8))),
// verified to agree with the fp32 reference at every integer delta.
// Capped for |delta| >= 91 -> 183-entry table covers all deltas.
// ---------------------------------------------------------------------------
__device__ __forceinline__ int t5_bucket(int delta) {
  int base = (delta > 0) ? 16 : 0;
  int a = delta < 0 ? -delta : delta;
  int n;
  if (a < 8)       n = a;
  else if (a < 12) n = 8;
  else if (a < 16) n = 9;
  else if (a < 23) n = 10;
  else if (a < 32) n = 11;
  else if (a < 46) n = 12;
  else if (a < 64) n = 13;
  else if (a < 91) n = 14;
  else             n = 15;
  return base + n;
}

// ---------------------------------------------------------------------------
// position_bias output: out[(h*S + q)*S + k] = table[bucket(k-q)*NH + h]
// Memory-bound 268 MB write; one row per block (write-BW-saturating shape).
// ---------------------------------------------------------------------------
__global__ __launch_bounds__(256) void bias_kernel(const float* __restrict__ table,
                                                   float* __restrict__ out) {
  int h = blockIdx.x >> 11;
  int q = blockIdx.x & (S_LEN - 1);
  __shared__ float tb[32];
  if (threadIdx.x < 32) tb[threadIdx.x] = table[threadIdx.x * NH + h];
  __syncthreads();
  float* dst = out + (size_t)blockIdx.x * S_LEN;
  int k0 = threadIdx.x * 4;
#pragma unroll
  for (int half = 0; half < 2; half++) {
    int k = k0 + half * 1024;
    float4 v;
    v.x = tb[t5_bucket((k + 0) - q)];
    v.y = tb[t5_bucket((k + 1) - q)];
    v.z = tb[t5_bucket((k + 2) - q)];
    v.w = tb[t5_bucket((k + 3) - q)];
    *(float4*)(dst + k) = v;
  }
}

// ---------------------------------------------------------------------------
// fp32 -> fp16 flat cast (hidden_states).
// ---------------------------------------------------------------------------
__global__ __launch_bounds__(256) void cast_f2h(const float* __restrict__ in,
                                                half_t* __restrict__ out) {
  int i = blockIdx.x * 256 + threadIdx.x;
  float4 v = ((const float4*)in)[i];
  halfx4 h;
  h[0] = (half_t)v.x; h[1] = (half_t)v.y; h[2] = (half_t)v.z; h[3] = (half_t)v.w;
  ((halfx4*)out)[i] = h;
}

// ---------------------------------------------------------------------------
// fp32 [R][C] -> fp16 [C][R] transpose+cast (weights). 32x32 LDS tile.
// ---------------------------------------------------------------------------
__global__ __launch_bounds__(256) void transpose_cast(const float* __restrict__ in,
                                                      half_t* __restrict__ out,
                                                      int R, int C) {
  __shared__ float t[32][33];
  int lr = threadIdx.x >> 3;
  int lc = (threadIdx.x & 7) * 4;
  int r0 = blockIdx.y * 32, c0 = blockIdx.x * 32;
  float4 v = *(const float4*)(in + (size_t)(r0 + lr) * C + c0 + lc);
  t[lr][lc + 0] = v.x; t[lr][lc + 1] = v.y; t[lr][lc + 2] = v.z; t[lr][lc + 3] = v.w;
  __syncthreads();
  halfx4 hv;
#pragma unroll
  for (int u = 0; u < 4; u++) hv[u] = (half_t)t[lc + u][lr];
  *(halfx4*)(out + (size_t)(c0 + lr) * R + r0 + lc) = hv;
}

// ---------------------------------------------------------------------------
// fp16 [b,h,s,d] -> [b,h,d,s] transpose (V). 64x64 tile per block.
// ---------------------------------------------------------------------------
__global__ __launch_bounds__(256) void vtrans(const half_t* __restrict__ V,
                                              half_t* __restrict__ Vt) {
  __shared__ half_t T[64 * 72];
  const int bh = blockIdx.y;
  const int s0 = blockIdx.x * 64;
  const half_t* src = V + ((size_t)bh * S_LEN + s0) * DKV;
  half_t* dst = Vt + (size_t)bh * DKV * S_LEN + s0;
  const int sr = threadIdx.x >> 3;        // 0..31
  const int dc = (threadIdx.x & 7) * 8;   // 0..56
#pragma unroll
  for (int p = 0; p < 2; p++) {
    int s = sr + p * 32;
    half8 v = *(const half8*)(src + (size_t)s * DKV + dc);
#pragma unroll
    for (int u = 0; u < 8; u++) T[(dc + u) * 72 + s] = v[u];
  }
  __syncthreads();
#pragma unroll
  for (int p = 0; p < 2; p++) {
    int d = sr + p * 32;
    half8 v = *(half8*)&T[d * 72 + dc];
    *(half8*)(dst + (size_t)d * S_LEN + dc) = v;
  }
}

// ---------------------------------------------------------------------------
// fp16 MFMA GEMM: C[M,N] = A[M,K] @ Bt[N,K]^T. 128x128 tile, BK=32, 256 thr
// (4 waves, 2x2), 4x4 mfma_f32_16x16x32_f16 frags per wave (m97 structure).
// MODE 0: fp32 store to C.
// MODE 1: QKV scatter epilogue -> fp16 [b,h,s,d]; Q PRE-SCALED by log2(e)
//         so attention softmax uses raw exp2.
// ---------------------------------------------------------------------------
template <int MODE>
__global__ __launch_bounds__(256) void hgemm128(const half_t* __restrict__ A,
                                                const half_t* __restrict__ Bt,
                                                float* __restrict__ C,
                                                half_t* __restrict__ Qo,
                                                half_t* __restrict__ Ko,
                                                half_t* __restrict__ Vo,
                                                int M, int N, int K) {
  __shared__ half_t Asl[8 * 512];
  __shared__ half_t Bsl[8 * 512];

  const int tid = threadIdx.x;
  const int w = tid >> 6;
  const int lane = tid & 63;
  const int l15 = lane & 15;
  const int quad = lane >> 4;
  const int wm = w >> 1, wn = w & 1;
  const int m0 = blockIdx.y * 128;
  const int n0 = blockIdx.x * 128;

  floatx4 acc[4][4];
#pragma unroll
  for (int i = 0; i < 4; i++)
#pragma unroll
    for (int j = 0; j < 4; j++) acc[i][j] = (floatx4){0.f, 0.f, 0.f, 0.f};

  const half_t* ga0 = A + (size_t)(m0 + (2 * w + 0) * 16 + l15) * K + quad * 8;
  const half_t* ga1 = A + (size_t)(m0 + (2 * w + 1) * 16 + l15) * K + quad * 8;
  const half_t* gb0 = Bt + (size_t)(n0 + (2 * w + 0) * 16 + l15) * K + quad * 8;
  const half_t* gb1 = Bt + (size_t)(n0 + (2 * w + 1) * 16 + l15) * K + quad * 8;
  half_t* la0 = &Asl[(2 * w + 0) * 512];
  half_t* la1 = &Asl[(2 * w + 1) * 512];
  half_t* lb0 = &Bsl[(2 * w + 0) * 512];
  half_t* lb1 = &Bsl[(2 * w + 1) * 512];

  for (int k0 = 0; k0 < K; k0 += 32) {
    __syncthreads();
    load_lds16(ga0 + k0, la0);
    load_lds16(ga1 + k0, la1);
    load_lds16(gb0 + k0, lb0);
    load_lds16(gb1 + k0, lb1);
    __syncthreads();

    half8 af[4], bf[4];
#pragma unroll
    for (int i = 0; i < 4; i++) af[i] = *(half8*)&Asl[(wm * 4 + i) * 512 + lane * 8];
#pragma unroll
    for (int j = 0; j < 4; j++) bf[j] = *(half8*)&Bsl[(wn * 4 + j) * 512 + lane * 8];
#pragma unroll
    for (int i = 0; i < 4; i++)
#pragma unroll
      for (int j = 0; j < 4; j++)
        acc[i][j] = __builtin_amdgcn_mfma_f32_16x16x32_f16(af[i], bf[j], acc[i][j], 0, 0, 0);
  }

  const int rowbase = m0 + wm * 64;
  const int colbase = n0 + wn * 64;
  if (MODE == 0) {
#pragma unroll
    for (int i = 0; i < 4; i++)
#pragma unroll
      for (int j = 0; j < 4; j++)
#pragma unroll
        for (int r = 0; r < 4; r++)
          C[(size_t)(rowbase + i * 16 + quad * 4 + r) * N + colbase + j * 16 + l15] =
              acc[i][j][r];
  } else {
    const int which = colbase >> 10;            // 0=q,1=k,2=v (uniform per wave)
    const int h = (colbase & 1023) >> 6;        // uniform per wave
    const int b = rowbase >> 11;
    const int s0 = rowbase & (S_LEN - 1);
    const float scale = (which == 0) ? LOG2E : 1.0f;   // Q pre-scaled for exp2
    half_t* base = ((which == 0) ? Qo : (which == 1) ? Ko : Vo) +
                   (size_t)(b * NH + h) * S_LEN * DKV;
#pragma unroll
    for (int i = 0; i < 4; i++)
#pragma unroll
      for (int j = 0; j < 4; j++)
#pragma unroll
        for (int r = 0; r < 4; r++)
          base[(size_t)(s0 + i * 16 + quad * 4 + r) * DKV + j * 16 + l15] =
              (half_t)(acc[i][j][r] * scale);
  }
}

// ---------------------------------------------------------------------------
// fp16 MFMA flash attention, NO split-K, 8 waves / 512 threads per block
// (128 queries/block -> K/V staged ONCE per 128 q: 268 MB total vs 537).
// S-TRANSPOSED register dataflow (no P LDS round-trip):
//
//   S^T = K Q^T via mfma_16x16x32 with A=K-frag, B=Q-frag. C-layout of S^T:
//   lane holds S[q=l15][key = nb*16 + quad*4 + r]. After exp2, p packs
//   DIRECTLY into the B-operand of mfma_f32_16x16x16f16 computing
//   O^T = V^T P^T (A = Vt b64 fragments from the swizzled Vts).
//
//   T14 async-STAGE: next tile's K/V loaded into regs right after the
//   ds_write barrier -> HBM/L3 latency hides under this tile's compute.
//   T13 (exact, THR=0): skip l/O rescale when running max didn't grow.
//   Softmax state (m,l) = ONE scalar per lane; reduce = 15 local fmax +
//   ds_swizzle(xor16) + shfl_xor(32). EXP2 domain (Q pre-scaled by log2e).
//   Epilogue divides by l and writes X fp16 directly (split-K partials,
//   Opart/Mp/Lp and the combine kernel are deleted).
// ---------------------------------------------------------------------------
__global__ __launch_bounds__(512) void attn_fused(const half_t* __restrict__ Q,
                                                  const half_t* __restrict__ K,
                                                  const half_t* __restrict__ Vt,
                                                  const float* __restrict__ table,
                                                  half_t* __restrict__ X) {
  __shared__ half_t Ks[64 * 64];    // [key][d] swizzled (8-half units ^ row&7)
  __shared__ half_t Vts[64 * 64];   // [d][key] swizzled
  __shared__ float tb[32];
  __shared__ float badd[184];       // log2e * bias by clamp(delta,-91,91)+91

  const int tid = threadIdx.x;
  const int w = tid >> 6;           // 0..7
  const int lane = tid & 63;
  const int l15 = lane & 15;
  const int quad = lane >> 4;
  const int bh = blockIdx.y;
  const int h = bh & (NH - 1);
  const int q0w = blockIdx.x * 128 + w * 16;

  if (tid < 32) tb[tid] = table[tid * NH + h] * LOG2E;
  __syncthreads();
  if (tid < 183) badd[tid] = tb[t5_bucket(tid - 91)];
  const float tb_neg = tb[15], tb_pos = tb[31];   // capped-region biases (scaled)

  // Q B-fragments: B[k=quad*8+j][n=l15] = Q[q0w+l15][...]
  half8 qf[2];
#pragma unroll
  for (int ks = 0; ks < 2; ks++)
    qf[ks] = *(const half8*)(Q + ((size_t)bh * S_LEN + q0w + l15) * DKV +
                             ks * 32 + quad * 8);

  // O^T accumulators: o[nb] holds O[q=l15][d = nb*16 + quad*4 + r]
  floatx4 o[4];
#pragma unroll
  for (int nb = 0; nb < 4; nb++) o[nb] = (floatx4){0.f, 0.f, 0.f, 0.f};
  float m = -1e30f, l = 0.0f;

  // staging: 512 thr x (16B K + 16B V); row jr = tid>>3, unit u = tid&7
  const int jr = tid >> 3;
  const int u = tid & 7;
  const int swu = (u ^ (jr & 7)) * 8;
  // S^T A-frag (K rows): addr = key*64 + ((ks*4+quad)^(key&7))*8, key=nb*16+l15
  const int kv_rd0 = l15 * 64 + ((0 * 4 + quad) ^ (l15 & 7)) * 8;
  const int kv_rd1 = l15 * 64 + ((1 * 4 + quad) ^ (l15 & 7)) * 8;
  // PV A-frag (Vt rows, b64): unit = kt*2 + (quad>>1), half-offset (quad&1)*4
  const int q2h = quad >> 1, q2l = (quad & 1) * 4;

  const half_t* Kg = K + ((size_t)bh * S_LEN + jr) * DKV + u * 8;
  const half_t* Vg = Vt + ((size_t)bh * DKV + jr) * S_LEN + u * 8;
  int rel = -q0w;   // kc - q0w, wave-uniform

  // T14: tile-0 K/V prefetched into regs before the loop
  half8 kreg = *(const half8*)Kg;
  half8 vreg = *(const half8*)Vg;

  for (int it = 0; it < 32; it++, rel += 64) {
    __syncthreads();                     // prev tile's LDS reads done
    *(half8*)&Ks[jr * 64 + swu] = kreg;  // (compiler waits vmcnt here)
    *(half8*)&Vts[jr * 64 + swu] = vreg;
    __syncthreads();
    if (it < 31) {                       // issue next tile's loads EARLY;
      Kg += 64 * DKV;                    // latency hides under compute below
      Vg += 64;
      kreg = *(const half8*)Kg;
      vreg = *(const half8*)Vg;
    }

    // ---- S^T = K Q'^T : s[nb][r] = S[q=l15][key = nb*16+quad*4+r] ----
    floatx4 s[4];
#pragma unroll
    for (int nb = 0; nb < 4; nb++) {
      s[nb] = (floatx4){0.f, 0.f, 0.f, 0.f};
      s[nb] = __builtin_amdgcn_mfma_f32_16x16x32_f16(
          *(half8*)&Ks[nb * 1024 + kv_rd0], qf[0], s[nb], 0, 0, 0);
      s[nb] = __builtin_amdgcn_mfma_f32_16x16x32_f16(
          *(half8*)&Ks[nb * 1024 + kv_rd1], qf[1], s[nb], 0, 0, 0);
    }

    // ---- online softmax (lane owns one q; reduce over quads) ----
    float cm = fmaxf(fmaxf(fmaxf(s[0][0], s[0][1]), fmaxf(s[0][2], s[0][3])),
                     fmaxf(fmaxf(s[1][0], s[1][1]), fmaxf(s[1][2], s[1][3])));
    cm = fmaxf(cm, fmaxf(fmaxf(fmaxf(s[2][0], s[2][1]), fmaxf(s[2][2], s[2][3])),
                         fmaxf(fmaxf(s[3][0], s[3][1]), fmaxf(s[3][2], s[3][3]))));
    {
      int i = __builtin_amdgcn_ds_swizzle(__float_as_int(cm), 0x401F);  // xor 16
      cm = fmaxf(cm, __int_as_float(i));
      cm = fmaxf(cm, __shfl_xor(cm, 32));
    }
    float mn = fmaxf(m, cm);
    // T13 exact: if max didn't grow for ANY lane of the wave, mn==m everywhere
    // -> the whole rescale pass is an arithmetic no-op; skip it.
    if (!__all(cm <= m)) {
      float al = exp2f(m - mn);
      l *= al;
#pragma unroll
      for (int nb = 0; nb < 4; nb++)
#pragma unroll
        for (int r = 0; r < 4; r++) o[nb][r] *= al;
      m = mn;
    }

    float lsum = 0.0f;
    halfx4 pvb[4];   // PV B-frags: pvb[kt][j] = p(key = kt*16 + quad*4 + j)
    if (rel >= 106 || rel <= -154) {
      const float sh = ((rel >= 106) ? tb_pos : tb_neg) - mn;
#pragma unroll
      for (int nb = 0; nb < 4; nb++)
#pragma unroll
        for (int r = 0; r < 4; r++) {
          float p = exp2f(s[nb][r] + sh);
          lsum += p;
          pvb[nb][r] = (half_t)p;
        }
    } else {
      const int db = rel + quad * 4 - l15 + 91;   // delta+91 at nb=0,r=0
#pragma unroll
      for (int nb = 0; nb < 4; nb++)
#pragma unroll
        for (int r = 0; r < 4; r++) {
          int idx = db + nb * 16 + r;
          idx = idx < 0 ? 0 : (idx > 182 ? 182 : idx);
          float p = exp2f(s[nb][r] - mn + badd[idx]);
          lsum += p;
          pvb[nb][r] = (half_t)p;
        }
    }
    {
      int i = __builtin_amdgcn_ds_swizzle(__float_as_int(lsum), 0x401F);
      lsum += __int_as_float(i);
      lsum += __shfl_xor(lsum, 32);
    }
    l += lsum;

    // ---- O^T += V^T P^T : 16 x mfma_16x16x16, A = Vt b64 frags ----
#pragma unroll
    for (int nb = 0; nb < 4; nb++) {
      const int vrow = (nb * 16 + l15);
      const int vsw = vrow & 7;
#pragma unroll
      for (int kt = 0; kt < 4; kt++) {
        halfx4 vf = *(halfx4*)&Vts[vrow * 64 + ((kt * 2 + q2h) ^ vsw) * 8 + q2l];
        o[nb] = __builtin_amdgcn_mfma_f32_16x16x16f16(vf, pvb[kt], o[nb], 0, 0, 0);
      }
    }
  }

  // ---- epilogue: divide by l, write X fp16 directly (no partials) ----
  {
    const float inv = 1.0f / l;
    const int b = bh >> 4;
    half_t* xp = X + (size_t)(b * S_LEN + q0w + l15) * DMODEL + h * DKV;
#pragma unroll
    for (int nb = 0; nb < 4; nb++) {
      halfx4 hv;
#pragma unroll
      for (int r = 0; r < 4; r++) hv[r] = (half_t)(o[nb][r] * inv);
      *(halfx4*)(xp + nb * 16 + quad * 4) = hv;
    }
  }
}

// ---------------------------------------------------------------------------
// kernel_launch
// ws layout (halves): Ah 4M (reused as Vt) | Wqt 3M | Wot 1M | Qh 4M | Kh 4M |
//   Vh 4M | Xh 4M   (~48 MB; split-K partials deleted)
// ---------------------------------------------------------------------------
extern "C" void kernel_launch(void* const* d_in, const int* in_sizes, int n_in,
                              void* d_out, int out_size, void* d_ws, size_t ws_size,
                              hipStream_t stream) {
  const float* hidden = (const float*)d_in[0];
  const float* w_qkv = (const float*)d_in[1];
  const float* w_o = (const float*)d_in[2];
  const float* table = (const float*)d_in[3];

  float* attn_out = (float*)d_out;
  float* bias_out = (float*)d_out + 4194304;

  half_t* Ah  = (half_t*)d_ws;     // hidden fp16; reused as Vt after QKV GEMM
  half_t* Wqt = Ah + 4194304;      // [3072][1024]
  half_t* Wot = Wqt + 3145728;     // [1024][1024]
  half_t* Qh  = Wot + 1048576;     // [b,h,s,d], pre-scaled by log2e
  half_t* Kh  = Qh + 4194304;      // [b,h,s,d]
  half_t* Vh  = Kh + 4194304;      // [b,h,s,d]
  half_t* Xh  = Vh + 4194304;      // [4096][1024]
  half_t* Vth = Ah;                // [b,h,d,s] (aliases Ah; Ah dead by then)

  // prep: casts + weight transposes + position_bias
  cast_f2h<<<4096, 256, 0, stream>>>(hidden, Ah);
  transpose_cast<<<dim3(3072 / 32, 1024 / 32), 256, 0, stream>>>(w_qkv, Wqt, 1024, 3072);
  transpose_cast<<<dim3(1024 / 32, 1024 / 32), 256, 0, stream>>>(w_o, Wot, 1024, 1024);
  bias_kernel<<<NH * S_LEN, 256, 0, stream>>>(table, bias_out);

  // QKV projection (fp16 MFMA; Q epilogue pre-scales by log2e)
  hgemm128<1><<<dim3(3072 / 128, 4096 / 128), 256, 0, stream>>>(
      Ah, Wqt, nullptr, Qh, Kh, Vh, 4096, 3072, 1024);

  // V -> Vt transpose (Ah is dead now; Vt aliases it)
  vtrans<<<dim3(S_LEN / 64, BATCH * NH), 256, 0, stream>>>(Vh, Vth);

  // fused fp16 MFMA flash attention (no split-K, T14 prefetch) -> Xh fp16
  attn_fused<<<dim3(S_LEN / 128, BATCH * NH), 512, 0, stream>>>(
      Qh, Kh, Vth, table, Xh);

  // output projection -> d_out fp32
  hgemm128<0><<<dim3(1024 / 128, 4096 / 128), 256, 0, stream>>>(
      Xh, Wot, attn_out, nullptr, nullptr, nullptr, 4096, 1024, 1024);
}

// Round 3
// 477.538 us; speedup vs baseline: 1.0418x; 1.0206x over previous
//
#include <hip/hip_runtime.h>
#include <hip/hip_bf16.h>
#include <cstdint>
#include <cstddef>

// Problem constants (T5 self-attention, B=2, S=2048, H=16, D=64, d_model=1024)
#define S_LEN 2048
#define NH 16
#define DKV 64
#define BATCH 2
#define DMODEL 1024
#define LOG2E 1.4426950408889634f

typedef _Float16 half_t;
typedef __attribute__((ext_vector_type(4))) _Float16 halfx4;  // 8 B (also 16x16x16 A/B frag)
typedef __attribute__((ext_vector_type(8))) _Float16 half8;   // 16x16x32 A/B frag (4 VGPRs)
typedef __attribute__((ext_vector_type(4))) float floatx4;    // MFMA C/D frag / 16B store

// async global->LDS, 16 B per lane; LDS dest = wave-uniform base + lane*16
__device__ __forceinline__ void load_lds16(const half_t* g, half_t* l) {
  __builtin_amdgcn_global_load_lds((const __attribute__((address_space(1))) void*)g,
                                   (__attribute__((address_space(3))) void*)l, 16, 0, 0);
}

// ---------------------------------------------------------------------------
// T5 relative-position bucket — EXACT integer thresholds (ceil(8*16^(n/8))),
// verified to agree with the fp32 reference at every integer delta.
// Handles ALL deltas (caps at bucket 15/31 for |delta| >= 91).
// ---------------------------------------------------------------------------
__device__ __forceinline__ int t5_bucket(int delta) {
  int base = (delta > 0) ? 16 : 0;
  int a = delta < 0 ? -delta : delta;
  int n;
  if (a < 8)       n = a;
  else if (a < 12) n = 8;
  else if (a < 16) n = 9;
  else if (a < 23) n = 10;
  else if (a < 32) n = 11;
  else if (a < 46) n = 12;
  else if (a < 64) n = 13;
  else if (a < 91) n = 14;
  else             n = 15;
  return base + n;
}

// ---------------------------------------------------------------------------
// position_bias output: out[(h*S + q)*S + k] = table[bucket(k-q)*NH + h]
// Memory-bound 268 MB write; one row per block; nontemporal (never re-read).
// ---------------------------------------------------------------------------
__global__ __launch_bounds__(256) void bias_kernel(const float* __restrict__ table,
                                                   float* __restrict__ out) {
  int h = blockIdx.x >> 11;
  int q = blockIdx.x & (S_LEN - 1);
  __shared__ float tb[32];
  if (threadIdx.x < 32) tb[threadIdx.x] = table[threadIdx.x * NH + h];
  __syncthreads();
  float* dst = out + (size_t)blockIdx.x * S_LEN;
  int k0 = threadIdx.x * 4;
#pragma unroll
  for (int half = 0; half < 2; half++) {
    int k = k0 + half * 1024;
    floatx4 v;
    v[0] = tb[t5_bucket((k + 0) - q)];
    v[1] = tb[t5_bucket((k + 1) - q)];
    v[2] = tb[t5_bucket((k + 2) - q)];
    v[3] = tb[t5_bucket((k + 3) - q)];
    __builtin_nontemporal_store(v, (floatx4*)(dst + k));
  }
}

// ---------------------------------------------------------------------------
// fp32 -> fp16 flat cast (hidden_states).
// ---------------------------------------------------------------------------
__global__ __launch_bounds__(256) void cast_f2h(const float* __restrict__ in,
                                                half_t* __restrict__ out) {
  int i = blockIdx.x * 256 + threadIdx.x;
  float4 v = ((const float4*)in)[i];
  halfx4 h;
  h[0] = (half_t)v.x; h[1] = (half_t)v.y; h[2] = (half_t)v.z; h[3] = (half_t)v.w;
  ((halfx4*)out)[i] = h;
}

// ---------------------------------------------------------------------------
// fp32 [R][C] -> fp16 [C][R] transpose+cast (weights). 32x32 LDS tile.
// ---------------------------------------------------------------------------
__global__ __launch_bounds__(256) void transpose_cast(const float* __restrict__ in,
                                                      half_t* __restrict__ out,
                                                      int R, int C) {
  __shared__ float t[32][33];
  int lr = threadIdx.x >> 3;
  int lc = (threadIdx.x & 7) * 4;
  int r0 = blockIdx.y * 32, c0 = blockIdx.x * 32;
  float4 v = *(const float4*)(in + (size_t)(r0 + lr) * C + c0 + lc);
  t[lr][lc + 0] = v.x; t[lr][lc + 1] = v.y; t[lr][lc + 2] = v.z; t[lr][lc + 3] = v.w;
  __syncthreads();
  halfx4 hv;
#pragma unroll
  for (int u = 0; u < 4; u++) hv[u] = (half_t)t[lc + u][lr];
  *(halfx4*)(out + (size_t)(c0 + lr) * R + r0 + lc) = hv;
}

// ---------------------------------------------------------------------------
// fp16 [b,h,s,d] -> [b,h,d,s] transpose (V). 64x64 tile per block.
// ---------------------------------------------------------------------------
__global__ __launch_bounds__(256) void vtrans(const half_t* __restrict__ V,
                                              half_t* __restrict__ Vt) {
  __shared__ half_t T[64 * 72];
  const int bh = blockIdx.y;
  const int s0 = blockIdx.x * 64;
  const half_t* src = V + ((size_t)bh * S_LEN + s0) * DKV;
  half_t* dst = Vt + (size_t)bh * DKV * S_LEN + s0;
  const int sr = threadIdx.x >> 3;        // 0..31
  const int dc = (threadIdx.x & 7) * 8;   // 0..56
#pragma unroll
  for (int p = 0; p < 2; p++) {
    int s = sr + p * 32;
    half8 v = *(const half8*)(src + (size_t)s * DKV + dc);
#pragma unroll
    for (int u = 0; u < 8; u++) T[(dc + u) * 72 + s] = v[u];
  }
  __syncthreads();
#pragma unroll
  for (int p = 0; p < 2; p++) {
    int d = sr + p * 32;
    half8 v = *(half8*)&T[d * 72 + dc];
    *(half8*)(dst + (size_t)d * S_LEN + dc) = v;
  }
}

// ---------------------------------------------------------------------------
// fp16 MFMA GEMM: C[M,N] = A[M,K] @ Bt[N,K]^T. 128x128 tile, BK=64 (16 K-steps
// at K=1024 -> half the barrier drains of BK=32), 256 thr (4 waves, 2x2),
// 4x4 mfma_f32_16x16x32_f16 frags per wave.
// SWAPPED operands (mfma(bf, af)): C comes out transposed so each lane holds
// 4 CONSECUTIVE columns -> vectorized float4 / halfx4 epilogue stores
// (row = ..+l15, col = ..+quad*4+r). Fragments are byte-identical; A/B frag
// register layouts are the same, only the operand order changes.
// MODE 0: fp32 float4 store to C.
// MODE 1: QKV scatter epilogue -> fp16 [b,h,s,d] halfx4 stores; Q PRE-SCALED
//         by log2(e) so attention softmax uses raw exp2.
// ---------------------------------------------------------------------------
template <int MODE>
__global__ __launch_bounds__(256) void hgemm128(const half_t* __restrict__ A,
                                                const half_t* __restrict__ Bt,
                                                float* __restrict__ C,
                                                half_t* __restrict__ Qo,
                                                half_t* __restrict__ Ko,
                                                half_t* __restrict__ Vo,
                                                int M, int N, int K) {
  __shared__ half_t Asl[8 * 1024];   // 8 row-blocks x (16 rows x 64 k), lane-linear panels
  __shared__ half_t Bsl[8 * 1024];

  const int tid = threadIdx.x;
  const int w = tid >> 6;
  const int lane = tid & 63;
  const int l15 = lane & 15;
  const int quad = lane >> 4;
  const int wm = w >> 1, wn = w & 1;
  const int m0 = blockIdx.y * 128;
  const int n0 = blockIdx.x * 128;

  floatx4 acc[4][4];
#pragma unroll
  for (int i = 0; i < 4; i++)
#pragma unroll
    for (int j = 0; j < 4; j++) acc[i][j] = (floatx4){0.f, 0.f, 0.f, 0.f};

  const half_t* ga0 = A + (size_t)(m0 + (2 * w + 0) * 16 + l15) * K + quad * 8;
  const half_t* ga1 = A + (size_t)(m0 + (2 * w + 1) * 16 + l15) * K + quad * 8;
  const half_t* gb0 = Bt + (size_t)(n0 + (2 * w + 0) * 16 + l15) * K + quad * 8;
  const half_t* gb1 = Bt + (size_t)(n0 + (2 * w + 1) * 16 + l15) * K + quad * 8;
  half_t* la0 = &Asl[(2 * w + 0) * 1024];
  half_t* la1 = &Asl[(2 * w + 1) * 1024];
  half_t* lb0 = &Bsl[(2 * w + 0) * 1024];
  half_t* lb1 = &Bsl[(2 * w + 1) * 1024];

  for (int k0 = 0; k0 < K; k0 += 64) {
    __syncthreads();
    load_lds16(ga0 + k0,      la0);
    load_lds16(ga0 + k0 + 32, la0 + 512);
    load_lds16(ga1 + k0,      la1);
    load_lds16(ga1 + k0 + 32, la1 + 512);
    load_lds16(gb0 + k0,      lb0);
    load_lds16(gb0 + k0 + 32, lb0 + 512);
    load_lds16(gb1 + k0,      lb1);
    load_lds16(gb1 + k0 + 32, lb1 + 512);
    __syncthreads();

#pragma unroll
    for (int ks = 0; ks < 2; ks++) {
      half8 af[4], bf[4];
#pragma unroll
      for (int i = 0; i < 4; i++)
        af[i] = *(half8*)&Asl[(wm * 4 + i) * 1024 + ks * 512 + lane * 8];
#pragma unroll
      for (int j = 0; j < 4; j++)
        bf[j] = *(half8*)&Bsl[(wn * 4 + j) * 1024 + ks * 512 + lane * 8];
#pragma unroll
      for (int i = 0; i < 4; i++)
#pragma unroll
        for (int j = 0; j < 4; j++)
          acc[i][j] = __builtin_amdgcn_mfma_f32_16x16x32_f16(bf[j], af[i], acc[i][j], 0, 0, 0);
    }
  }

  // transposed C layout: lane holds C[row = rowbase+i*16+l15][col = colbase+j*16+quad*4 + r]
  const int rowbase = m0 + wm * 64;
  const int colbase = n0 + wn * 64;
  if (MODE == 0) {
#pragma unroll
    for (int i = 0; i < 4; i++)
#pragma unroll
      for (int j = 0; j < 4; j++)
        *(floatx4*)&C[(size_t)(rowbase + i * 16 + l15) * N + colbase + j * 16 + quad * 4] =
            acc[i][j];
  } else {
    const int which = colbase >> 10;            // 0=q,1=k,2=v (uniform per wave)
    const int h = (colbase & 1023) >> 6;        // uniform per wave
    const int b = rowbase >> 11;
    const int s0 = rowbase & (S_LEN - 1);
    const float scale = (which == 0) ? LOG2E : 1.0f;   // Q pre-scaled for exp2
    half_t* base = ((which == 0) ? Qo : (which == 1) ? Ko : Vo) +
                   (size_t)(b * NH + h) * S_LEN * DKV;
#pragma unroll
    for (int i = 0; i < 4; i++)
#pragma unroll
      for (int j = 0; j < 4; j++) {
        halfx4 hv;
#pragma unroll
        for (int r = 0; r < 4; r++) hv[r] = (half_t)(acc[i][j][r] * scale);
        *(halfx4*)&base[(size_t)(s0 + i * 16 + l15) * DKV + j * 16 + quad * 4] = hv;
      }
  }
}

// ---------------------------------------------------------------------------
// fp16 MFMA flash attention, 8 waves / 512 threads, 128 q/block, no split-K.
// S-TRANSPOSED register dataflow; T14 async-STAGE reg prefetch; T13 exact
// rescale skip. This round:
//  - bias folded into MFMA C-in via extended 337-entry table (no clamps,
//    no post-MFMA bias adds) for interior tiles;
//  - per-lane partial l (cross-quad lsum reduce deferred to epilogue; the
//    rescale factor al is quad-uniform so partials stay exact).
// ---------------------------------------------------------------------------
__global__ __launch_bounds__(512) void attn_fused(const half_t* __restrict__ Q,
                                                  const half_t* __restrict__ K,
                                                  const half_t* __restrict__ Vt,
                                                  const float* __restrict__ table,
                                                  half_t* __restrict__ X) {
  __shared__ half_t Ks[64 * 64];    // [key][d] swizzled (8-half units ^ row&7)
  __shared__ half_t Vts[64 * 64];   // [d][key] swizzled
  __shared__ float tb[32];
  __shared__ float badd2[344];      // log2e*bias by delta+168, delta in [-168,168]

  const int tid = threadIdx.x;
  const int w = tid >> 6;           // 0..7
  const int lane = tid & 63;
  const int l15 = lane & 15;
  const int quad = lane >> 4;
  const int bh = blockIdx.y;
  const int h = bh & (NH - 1);
  const int q0w = blockIdx.x * 128 + w * 16;

  if (tid < 32) tb[tid] = table[tid * NH + h] * LOG2E;
  __syncthreads();
  if (tid < 337) badd2[tid] = tb[t5_bucket(tid - 168)];
  const float tb_neg = tb[15], tb_pos = tb[31];   // capped-region biases (scaled)

  // Q B-fragments: B[k=quad*8+j][n=l15] = Q[q0w+l15][...]
  half8 qf[2];
#pragma unroll
  for (int ks = 0; ks < 2; ks++)
    qf[ks] = *(const half8*)(Q + ((size_t)bh * S_LEN + q0w + l15) * DKV +
                             ks * 32 + quad * 8);

  // O^T accumulators: o[nb] holds O[q=l15][d = nb*16 + quad*4 + r]
  floatx4 o[4];
#pragma unroll
  for (int nb = 0; nb < 4; nb++) o[nb] = (floatx4){0.f, 0.f, 0.f, 0.f};
  float m = -1e30f, l = 0.0f;       // l is PER-LANE PARTIAL (this quad's keys)

  // staging: 512 thr x (16B K + 16B V); row jr = tid>>3, unit u = tid&7
  const int jr = tid >> 3;
  const int u = tid & 7;
  const int swu = (u ^ (jr & 7)) * 8;
  // S^T A-frag (K rows): addr = key*64 + ((ks*4+quad)^(key&7))*8, key=nb*16+l15
  const int kv_rd0 = l15 * 64 + ((0 * 4 + quad) ^ (l15 & 7)) * 8;
  const int kv_rd1 = l15 * 64 + ((1 * 4 + quad) ^ (l15 & 7)) * 8;
  // PV A-frag (Vt rows, b64): unit = kt*2 + (quad>>1), half-offset (quad&1)*4
  const int q2h = quad >> 1, q2l = (quad & 1) * 4;

  const half_t* Kg = K + ((size_t)bh * S_LEN + jr) * DKV + u * 8;
  const half_t* Vg = Vt + ((size_t)bh * DKV + jr) * S_LEN + u * 8;
  int rel = -q0w;   // kc - q0w, wave-uniform

  // T14: tile-0 K/V prefetched into regs before the loop
  half8 kreg = *(const half8*)Kg;
  half8 vreg = *(const half8*)Vg;

  for (int it = 0; it < 32; it++, rel += 64) {
    __syncthreads();                     // prev tile's LDS reads done
    *(half8*)&Ks[jr * 64 + swu] = kreg;  // (compiler waits vmcnt here)
    *(half8*)&Vts[jr * 64 + swu] = vreg;
    __syncthreads();
    if (it < 31) {                       // issue next tile's loads EARLY;
      Kg += 64 * DKV;                    // latency hides under compute below
      Vg += 64;
      kreg = *(const half8*)Kg;
      vreg = *(const half8*)Vg;
    }

    // ---- S^T = K Q'^T (+bias in C-in for interior tiles) ----
    // s[nb][r] = S[q=l15][key = nb*16+quad*4+r]
    const bool capped = (rel >= 106 || rel <= -154);
    floatx4 s[4];
    if (capped) {
#pragma unroll
      for (int nb = 0; nb < 4; nb++) s[nb] = (floatx4){0.f, 0.f, 0.f, 0.f};
    } else {
      const int db = rel + quad * 4 - l15 + 168;   // idx at nb=0,r=0; in [0,336]
#pragma unroll
      for (int nb = 0; nb < 4; nb++) {
        s[nb][0] = badd2[db + nb * 16 + 0];
        s[nb][1] = badd2[db + nb * 16 + 1];
        s[nb][2] = badd2[db + nb * 16 + 2];
        s[nb][3] = badd2[db + nb * 16 + 3];
      }
    }
#pragma unroll
    for (int nb = 0; nb < 4; nb++) {
      s[nb] = __builtin_amdgcn_mfma_f32_16x16x32_f16(
          *(half8*)&Ks[nb * 1024 + kv_rd0], qf[0], s[nb], 0, 0, 0);
      s[nb] = __builtin_amdgcn_mfma_f32_16x16x32_f16(
          *(half8*)&Ks[nb * 1024 + kv_rd1], qf[1], s[nb], 0, 0, 0);
    }

    // ---- online softmax (lane owns one q; max reduce over quads) ----
    float cm = fmaxf(fmaxf(fmaxf(s[0][0], s[0][1]), fmaxf(s[0][2], s[0][3])),
                     fmaxf(fmaxf(s[1][0], s[1][1]), fmaxf(s[1][2], s[1][3])));
    cm = fmaxf(cm, fmaxf(fmaxf(fmaxf(s[2][0], s[2][1]), fmaxf(s[2][2], s[2][3])),
                         fmaxf(fmaxf(s[3][0], s[3][1]), fmaxf(s[3][2], s[3][3]))));
    {
      int i = __builtin_amdgcn_ds_swizzle(__float_as_int(cm), 0x401F);  // xor 16
      cm = fmaxf(cm, __int_as_float(i));
      cm = fmaxf(cm, __shfl_xor(cm, 32));
    }
    // T13 exact: if max didn't grow for ANY lane of the wave, the rescale is
    // an arithmetic no-op (mn==m for every lane); skip it.
    if (!__all(cm <= m)) {
      float mn = fmaxf(m, cm);
      float al = exp2f(m - mn);
      l *= al;
#pragma unroll
      for (int nb = 0; nb < 4; nb++)
#pragma unroll
        for (int r = 0; r < 4; r++) o[nb][r] *= al;
      m = mn;
    }

    float lsum = 0.0f;
    halfx4 pvb[4];   // PV B-frags: pvb[kt][j] = p(key = kt*16 + quad*4 + j)
    if (capped) {
      const float sh = ((rel >= 106) ? tb_pos : tb_neg) - m;
#pragma unroll
      for (int nb = 0; nb < 4; nb++)
#pragma unroll
        for (int r = 0; r < 4; r++) {
          float p = exp2f(s[nb][r] + sh);
          lsum += p;
          pvb[nb][r] = (half_t)p;
        }
    } else {
#pragma unroll
      for (int nb = 0; nb < 4; nb++)
#pragma unroll
        for (int r = 0; r < 4; r++) {
          float p = exp2f(s[nb][r] - m);   // bias already inside s
          lsum += p;
          pvb[nb][r] = (half_t)p;
        }
    }
    l += lsum;   // per-lane partial; cross-quad reduce deferred to epilogue

    // ---- O^T += V^T P^T : 16 x mfma_16x16x16, A = Vt b64 frags ----
#pragma unroll
    for (int nb = 0; nb < 4; nb++) {
      const int vrow = (nb * 16 + l15);
      const int vsw = vrow & 7;
#pragma unroll
      for (int kt = 0; kt < 4; kt++) {
        halfx4 vf = *(halfx4*)&Vts[vrow * 64 + ((kt * 2 + q2h) ^ vsw) * 8 + q2l];
        o[nb] = __builtin_amdgcn_mfma_f32_16x16x16f16(vf, pvb[kt], o[nb], 0, 0, 0);
      }
    }
  }

  // ---- epilogue: reduce l across quads, divide, write X fp16 directly ----
  {
    int i = __builtin_amdgcn_ds_swizzle(__float_as_int(l), 0x401F);   // xor 16
    l += __int_as_float(i);
    l += __shfl_xor(l, 32);
    const float inv = 1.0f / l;
    const int b = bh >> 4;
    half_t* xp = X + (size_t)(b * S_LEN + q0w + l15) * DMODEL + h * DKV;
#pragma unroll
    for (int nb = 0; nb < 4; nb++) {
      halfx4 hv;
#pragma unroll
      for (int r = 0; r < 4; r++) hv[r] = (half_t)(o[nb][r] * inv);
      *(halfx4*)(xp + nb * 16 + quad * 4) = hv;
    }
  }
}

// ---------------------------------------------------------------------------
// kernel_launch
// ws layout (halves): Ah 4M (reused as Vt) | Wqt 3M | Wot 1M | Qh 4M | Kh 4M |
//   Vh 4M | Xh 4M   (~48 MB)
// ---------------------------------------------------------------------------
extern "C" void kernel_launch(void* const* d_in, const int* in_sizes, int n_in,
                              void* d_out, int out_size, void* d_ws, size_t ws_size,
                              hipStream_t stream) {
  const float* hidden = (const float*)d_in[0];
  const float* w_qkv = (const float*)d_in[1];
  const float* w_o = (const float*)d_in[2];
  const float* table = (const float*)d_in[3];

  float* attn_out = (float*)d_out;
  float* bias_out = (float*)d_out + 4194304;

  half_t* Ah  = (half_t*)d_ws;     // hidden fp16; reused as Vt after QKV GEMM
  half_t* Wqt = Ah + 4194304;      // [3072][1024]
  half_t* Wot = Wqt + 3145728;     // [1024][1024]
  half_t* Qh  = Wot + 1048576;     // [b,h,s,d], pre-scaled by log2e
  half_t* Kh  = Qh + 4194304;      // [b,h,s,d]
  half_t* Vh  = Kh + 4194304;      // [b,h,s,d]
  half_t* Xh  = Vh + 4194304;      // [4096][1024]
  half_t* Vth = Ah;                // [b,h,d,s] (aliases Ah; Ah dead by then)

  // prep: casts + weight transposes + position_bias
  cast_f2h<<<4096, 256, 0, stream>>>(hidden, Ah);
  transpose_cast<<<dim3(3072 / 32, 1024 / 32), 256, 0, stream>>>(w_qkv, Wqt, 1024, 3072);
  transpose_cast<<<dim3(1024 / 32, 1024 / 32), 256, 0, stream>>>(w_o, Wot, 1024, 1024);
  bias_kernel<<<NH * S_LEN, 256, 0, stream>>>(table, bias_out);

  // QKV projection (fp16 MFMA; Q epilogue pre-scales by log2e)
  hgemm128<1><<<dim3(3072 / 128, 4096 / 128), 256, 0, stream>>>(
      Ah, Wqt, nullptr, Qh, Kh, Vh, 4096, 3072, 1024);

  // V -> Vt transpose (Ah is dead now; Vt aliases it)
  vtrans<<<dim3(S_LEN / 64, BATCH * NH), 256, 0, stream>>>(Vh, Vth);

  // fused fp16 MFMA flash attention -> Xh fp16
  attn_fused<<<dim3(S_LEN / 128, BATCH * NH), 512, 0, stream>>>(
      Qh, Kh, Vth, table, Xh);

  // output projection -> d_out fp32
  hgemm128<0><<<dim3(1024 / 128, 4096 / 128), 256, 0, stream>>>(
      Xh, Wot, attn_out, nullptr, nullptr, nullptr, 4096, 1024, 1024);
}

// Round 5
// 468.983 us; speedup vs baseline: 1.0608x; 1.0182x over previous
//
#include <hip/hip_runtime.h>
#include <hip/hip_bf16.h>
#include <cstdint>
#include <cstddef>

// Problem constants (T5 self-attention, B=2, S=2048, H=16, D=64, d_model=1024)
#define S_LEN 2048
#define NH 16
#define DKV 64
#define BATCH 2
#define DMODEL 1024
#define LOG2E 1.4426950408889634f

typedef _Float16 half_t;
typedef __attribute__((ext_vector_type(2))) __fp16 fp16x2;    // cvt_pkrtz result type
typedef __attribute__((ext_vector_type(4))) __fp16 fp16x4;
typedef __attribute__((ext_vector_type(4))) _Float16 halfx4;  // 8 B (also 16x16x16 A/B frag)
typedef __attribute__((ext_vector_type(8))) _Float16 half8;   // 16x16x32 A/B frag (4 VGPRs)
typedef __attribute__((ext_vector_type(4))) float floatx4;    // MFMA C/D frag / 16B store

// async global->LDS, 16 B per lane; LDS dest = wave-uniform base + lane*16
__device__ __forceinline__ void load_lds16(const half_t* g, half_t* l) {
  __builtin_amdgcn_global_load_lds((const __attribute__((address_space(1))) void*)g,
                                   (__attribute__((address_space(3))) void*)l, 16, 0, 0);
}

// ---------------------------------------------------------------------------
// T5 relative-position bucket — EXACT integer thresholds (ceil(8*16^(n/8))),
// verified to agree with the fp32 reference at every integer delta.
// Handles ALL deltas (caps at bucket 15/31 for |delta| >= 91).
// ---------------------------------------------------------------------------
__device__ __forceinline__ int t5_bucket(int delta) {
  int base = (delta > 0) ? 16 : 0;
  int a = delta < 0 ? -delta : delta;
  int n;
  if (a < 8)       n = a;
  else if (a < 12) n = 8;
  else if (a < 16) n = 9;
  else if (a < 23) n = 10;
  else if (a < 32) n = 11;
  else if (a < 46) n = 12;
  else if (a < 64) n = 13;
  else if (a < 91) n = 14;
  else             n = 15;
  return base + n;
}

// ---------------------------------------------------------------------------
// FUSED prep: ONE dispatch covering
//   blocks [0, 32768)        : position_bias rows (268 MB nontemporal write)
//   blocks [32768, 36864)    : hidden fp32 -> fp16 flat cast
//   blocks [36864, 39936)    : w_qkv fp32 [1024][3072] -> fp16 [3072][1024]
//   blocks [39936, 40960)    : w_o   fp32 [1024][1024] -> fp16 [1024][1024]^T
// All independent; fusing saves 3 kernel launches.
// ---------------------------------------------------------------------------
__global__ __launch_bounds__(256) void prep_all(const float* __restrict__ hidden,
                                                const float* __restrict__ w_qkv,
                                                const float* __restrict__ w_o,
                                                const float* __restrict__ table,
                                                half_t* __restrict__ Ah,
                                                half_t* __restrict__ Wqt,
                                                half_t* __restrict__ Wot,
                                                float* __restrict__ bias_out) {
  __shared__ float smem[32 * 33];
  const int id = blockIdx.x;
  const int tid = threadIdx.x;

  if (id < 32768) {
    // ---- position_bias row: out[(h*S+q)*S + k] = table[bucket(k-q)*NH + h]
    const int h = id >> 11;
    const int q = id & (S_LEN - 1);
    if (tid < 32) smem[tid] = table[tid * NH + h];
    __syncthreads();
    float* dst = bias_out + (size_t)id * S_LEN;
    const int k0 = tid * 4;
#pragma unroll
    for (int hf = 0; hf < 2; hf++) {
      int k = k0 + hf * 1024;
      floatx4 v;
      v[0] = smem[t5_bucket((k + 0) - q)];
      v[1] = smem[t5_bucket((k + 1) - q)];
      v[2] = smem[t5_bucket((k + 2) - q)];
      v[3] = smem[t5_bucket((k + 3) - q)];
      __builtin_nontemporal_store(v, (floatx4*)(dst + k));
    }
  } else if (id < 36864) {
    // ---- fp32 -> fp16 flat cast (hidden_states)
    const int i = (id - 32768) * 256 + tid;
    float4 v = ((const float4*)hidden)[i];
    halfx4 hv;
    hv[0] = (half_t)v.x; hv[1] = (half_t)v.y; hv[2] = (half_t)v.z; hv[3] = (half_t)v.w;
    ((halfx4*)Ah)[i] = hv;
  } else {
    // ---- fp32 [R][C] -> fp16 [C][R] transpose+cast (weights), 32x32 tile
    const float* in;
    half_t* out;
    int R, C, bx, by;
    if (id < 39936) {
      int t = id - 36864; bx = t % 96; by = t / 96;
      in = w_qkv; out = Wqt; R = 1024; C = 3072;
    } else {
      int t = id - 39936; bx = t & 31; by = t >> 5;
      in = w_o; out = Wot; R = 1024; C = 1024;
    }
    float (*t33)[33] = (float(*)[33])smem;
    const int lr = tid >> 3;
    const int lc = (tid & 7) * 4;
    const int r0 = by * 32, c0 = bx * 32;
    float4 v = *(const float4*)(in + (size_t)(r0 + lr) * C + c0 + lc);
    t33[lr][lc + 0] = v.x; t33[lr][lc + 1] = v.y;
    t33[lr][lc + 2] = v.z; t33[lr][lc + 3] = v.w;
    __syncthreads();
    halfx4 hv;
#pragma unroll
    for (int u = 0; u < 4; u++) hv[u] = (half_t)t33[lc + u][lr];
    *(halfx4*)(out + (size_t)(c0 + lr) * R + r0 + lc) = hv;
  }
}

// ---------------------------------------------------------------------------
// fp16 [b,h,s,d] -> [b,h,d,s] transpose (V). 64x64 tile per block.
// ---------------------------------------------------------------------------
__global__ __launch_bounds__(256) void vtrans(const half_t* __restrict__ V,
                                              half_t* __restrict__ Vt) {
  __shared__ half_t T[64 * 72];
  const int bh = blockIdx.y;
  const int s0 = blockIdx.x * 64;
  const half_t* src = V + ((size_t)bh * S_LEN + s0) * DKV;
  half_t* dst = Vt + (size_t)bh * DKV * S_LEN + s0;
  const int sr = threadIdx.x >> 3;        // 0..31
  const int dc = (threadIdx.x & 7) * 8;   // 0..56
#pragma unroll
  for (int p = 0; p < 2; p++) {
    int s = sr + p * 32;
    half8 v = *(const half8*)(src + (size_t)s * DKV + dc);
#pragma unroll
    for (int u = 0; u < 8; u++) T[(dc + u) * 72 + s] = v[u];
  }
  __syncthreads();
#pragma unroll
  for (int p = 0; p < 2; p++) {
    int d = sr + p * 32;
    half8 v = *(half8*)&T[d * 72 + dc];
    *(half8*)(dst + (size_t)d * S_LEN + dc) = v;
  }
}

// ---------------------------------------------------------------------------
// fp16 MFMA GEMM: C[M,N] = A[M,K] @ Bt[N,K]^T. 128x128 tile, BK=64, 256 thr
// (4 waves, 2x2), 4x4 mfma_f32_16x16x32_f16 frags per wave.
// SWAPPED operands (mfma(bf, af)): C transposed -> each lane holds 4
// CONSECUTIVE columns -> vectorized float4 / halfx4 epilogue stores.
// MODE 0: fp32 float4 store to C.
// MODE 1: QKV scatter -> fp16 [b,h,s,d]; Q PRE-SCALED by log2(e).
// ---------------------------------------------------------------------------
template <int MODE>
__global__ __launch_bounds__(256) void hgemm128(const half_t* __restrict__ A,
                                                const half_t* __restrict__ Bt,
                                                float* __restrict__ C,
                                                half_t* __restrict__ Qo,
                                                half_t* __restrict__ Ko,
                                                half_t* __restrict__ Vo,
                                                int M, int N, int K) {
  __shared__ half_t Asl[8 * 1024];   // 8 row-blocks x (16 rows x 64 k), lane-linear panels
  __shared__ half_t Bsl[8 * 1024];

  const int tid = threadIdx.x;
  const int w = tid >> 6;
  const int lane = tid & 63;
  const int l15 = lane & 15;
  const int quad = lane >> 4;
  const int wm = w >> 1, wn = w & 1;
  const int m0 = blockIdx.y * 128;
  const int n0 = blockIdx.x * 128;

  floatx4 acc[4][4];
#pragma unroll
  for (int i = 0; i < 4; i++)
#pragma unroll
    for (int j = 0; j < 4; j++) acc[i][j] = (floatx4){0.f, 0.f, 0.f, 0.f};

  const half_t* ga0 = A + (size_t)(m0 + (2 * w + 0) * 16 + l15) * K + quad * 8;
  const half_t* ga1 = A + (size_t)(m0 + (2 * w + 1) * 16 + l15) * K + quad * 8;
  const half_t* gb0 = Bt + (size_t)(n0 + (2 * w + 0) * 16 + l15) * K + quad * 8;
  const half_t* gb1 = Bt + (size_t)(n0 + (2 * w + 1) * 16 + l15) * K + quad * 8;
  half_t* la0 = &Asl[(2 * w + 0) * 1024];
  half_t* la1 = &Asl[(2 * w + 1) * 1024];
  half_t* lb0 = &Bsl[(2 * w + 0) * 1024];
  half_t* lb1 = &Bsl[(2 * w + 1) * 1024];

  for (int k0 = 0; k0 < K; k0 += 64) {
    __syncthreads();
    load_lds16(ga0 + k0,      la0);
    load_lds16(ga0 + k0 + 32, la0 + 512);
    load_lds16(ga1 + k0,      la1);
    load_lds16(ga1 + k0 + 32, la1 + 512);
    load_lds16(gb0 + k0,      lb0);
    load_lds16(gb0 + k0 + 32, lb0 + 512);
    load_lds16(gb1 + k0,      lb1);
    load_lds16(gb1 + k0 + 32, lb1 + 512);
    __syncthreads();

#pragma unroll
    for (int ks = 0; ks < 2; ks++) {
      half8 af[4], bf[4];
#pragma unroll
      for (int i = 0; i < 4; i++)
        af[i] = *(half8*)&Asl[(wm * 4 + i) * 1024 + ks * 512 + lane * 8];
#pragma unroll
      for (int j = 0; j < 4; j++)
        bf[j] = *(half8*)&Bsl[(wn * 4 + j) * 1024 + ks * 512 + lane * 8];
#pragma unroll
      for (int i = 0; i < 4; i++)
#pragma unroll
        for (int j = 0; j < 4; j++)
          acc[i][j] = __builtin_amdgcn_mfma_f32_16x16x32_f16(bf[j], af[i], acc[i][j], 0, 0, 0);
    }
  }

  // transposed C layout: lane holds C[row = rowbase+i*16+l15][col = colbase+j*16+quad*4 + r]
  const int rowbase = m0 + wm * 64;
  const int colbase = n0 + wn * 64;
  if (MODE == 0) {
#pragma unroll
    for (int i = 0; i < 4; i++)
#pragma unroll
      for (int j = 0; j < 4; j++)
        *(floatx4*)&C[(size_t)(rowbase + i * 16 + l15) * N + colbase + j * 16 + quad * 4] =
            acc[i][j];
  } else {
    const int which = colbase >> 10;            // 0=q,1=k,2=v (uniform per wave)
    const int h = (colbase & 1023) >> 6;        // uniform per wave
    const int b = rowbase >> 11;
    const int s0 = rowbase & (S_LEN - 1);
    const float scale = (which == 0) ? LOG2E : 1.0f;   // Q pre-scaled for exp2
    half_t* base = ((which == 0) ? Qo : (which == 1) ? Ko : Vo) +
                   (size_t)(b * NH + h) * S_LEN * DKV;
#pragma unroll
    for (int i = 0; i < 4; i++)
#pragma unroll
      for (int j = 0; j < 4; j++) {
        halfx4 hv;
#pragma unroll
        for (int r = 0; r < 4; r++) hv[r] = (half_t)(acc[i][j][r] * scale);
        *(halfx4*)&base[(size_t)(s0 + i * 16 + l15) * DKV + j * 16 + quad * 4] = hv;
      }
  }
}

// ---------------------------------------------------------------------------
// fp16 MFMA flash attention, 8 waves / 512 threads, 128 q/block.
//  - 128 keys staged per barrier pair (two 64-key buffers, identical layout)
//    -> barrier pairs halved (32 -> 16), deeper T14 prefetch;
//  - bias C-in via 4-phase float4-aligned table -> 4x ds_read_b128 per tile;
//  - max-reduce restructured for v_max3 fusion;
//  - P f32->f16 via v_cvt_pkrtz (bit_cast to MFMA frag type);
//  - unified capped/interior exp2 loop.
// ---------------------------------------------------------------------------
__global__ __launch_bounds__(512) void attn_fused(const half_t* __restrict__ Q,
                                                  const half_t* __restrict__ K,
                                                  const half_t* __restrict__ Vt,
                                                  const float* __restrict__ table,
                                                  half_t* __restrict__ X) {
  __shared__ half_t Ks[2 * 64 * 64];    // two [key][d] buffers, swizzled
  __shared__ half_t Vts[2 * 64 * 64];   // two [d][key] buffers, swizzled
  __shared__ float tb[32];
  __shared__ floatx4 badd4[352];        // 4 phase-copies x 88 float4 of
                                        // log2e*bias by (delta+168), aligned

  const int tid = threadIdx.x;
  const int w = tid >> 6;           // 0..7
  const int lane = tid & 63;
  const int l15 = lane & 15;
  const int quad = lane >> 4;
  const int bh = blockIdx.y;
  const int h = bh & (NH - 1);
  const int q0w = blockIdx.x * 128 + w * 16;

  if (tid < 32) tb[tid] = table[tid * NH + h] * LOG2E;
  __syncthreads();
  if (tid < 352) {
    const int p = tid / 88, t = tid - p * 88;
    floatx4 v;
#pragma unroll
    for (int e = 0; e < 4; e++) {
      int lin = p + 4 * t + e;
      if (lin > 343) lin = 343;
      v[e] = tb[t5_bucket(lin - 168)];
    }
    badd4[tid] = v;    // first consumer is after the loop's double barrier
  }
  const float tb_neg = tb[15], tb_pos = tb[31];   // capped-region biases (scaled)

  // Q B-fragments: B[k=quad*8+j][n=l15] = Q[q0w+l15][...]
  half8 qf[2];
#pragma unroll
  for (int ks = 0; ks < 2; ks++)
    qf[ks] = *(const half8*)(Q + ((size_t)bh * S_LEN + q0w + l15) * DKV +
                             ks * 32 + quad * 8);

  // O^T accumulators: o[nb] holds O[q=l15][d = nb*16 + quad*4 + r]
  floatx4 o[4];
#pragma unroll
  for (int nb = 0; nb < 4; nb++) o[nb] = (floatx4){0.f, 0.f, 0.f, 0.f};
  float m = -1e30f, l = 0.0f;       // l is PER-LANE PARTIAL (this quad's keys)

  // staging: 512 thr x 2x(16B K + 16B V); row jr = tid>>3, unit u = tid&7
  const int jr = tid >> 3;
  const int u = tid & 7;
  const int swu = (u ^ (jr & 7)) * 8;
  // S^T A-frag (K rows): addr = key*64 + ((ks*4+quad)^(key&7))*8, key=nb*16+l15
  const int kv_rd0 = l15 * 64 + ((0 * 4 + quad) ^ (l15 & 7)) * 8;
  const int kv_rd1 = l15 * 64 + ((1 * 4 + quad) ^ (l15 & 7)) * 8;
  // PV A-frag (Vt rows, b64): unit = kt*2 + (quad>>1), half-offset (quad&1)*4
  const int q2h = quad >> 1, q2l = (quad & 1) * 4;

  const half_t* Kg = K + ((size_t)bh * S_LEN + jr) * DKV + u * 8;
  const half_t* Vg = Vt + ((size_t)bh * DKV + jr) * S_LEN + u * 8;
  int rel = -q0w;   // kc - q0w, wave-uniform

  // T14: tile-pair 0 K/V prefetched into regs before the loop
  half8 kreg0 = *(const half8*)Kg;
  half8 kreg1 = *(const half8*)(Kg + 64 * DKV);
  half8 vreg0 = *(const half8*)Vg;
  half8 vreg1 = *(const half8*)(Vg + 64);

  for (int it = 0; it < 16; it++, rel += 128) {
    __syncthreads();                     // prev tiles' LDS reads done
    *(half8*)&Ks[jr * 64 + swu] = kreg0;
    *(half8*)&Ks[4096 + jr * 64 + swu] = kreg1;
    *(half8*)&Vts[jr * 64 + swu] = vreg0;
    *(half8*)&Vts[4096 + jr * 64 + swu] = vreg1;
    __syncthreads();
    if (it < 15) {                       // issue next pair's loads EARLY
      Kg += 128 * DKV;
      Vg += 128;
      kreg0 = *(const half8*)Kg;
      kreg1 = *(const half8*)(Kg + 64 * DKV);
      vreg0 = *(const half8*)Vg;
      vreg1 = *(const half8*)(Vg + 64);
    }

#pragma unroll
    for (int hb = 0; hb < 2; hb++) {
      const int relh = rel + hb * 64;
      const half_t* Kb = &Ks[hb * 4096];
      const half_t* Vb = &Vts[hb * 4096];

      // ---- S^T = K Q'^T (+bias in C-in for interior tiles) ----
      const bool capped = (relh >= 106 || relh <= -154);
      floatx4 s[4];
      if (capped) {
#pragma unroll
        for (int nb = 0; nb < 4; nb++) s[nb] = (floatx4){0.f, 0.f, 0.f, 0.f};
      } else {
        const int db = relh + quad * 4 - l15 + 168;   // in [9, 276]
        const int ph = db & 3;
        const int bb = db >> 2;
#pragma unroll
        for (int nb = 0; nb < 4; nb++) s[nb] = badd4[ph * 88 + bb + nb * 4];
      }
#pragma unroll
      for (int nb = 0; nb < 4; nb++) {
        s[nb] = __builtin_amdgcn_mfma_f32_16x16x32_f16(
            *(half8*)&Kb[nb * 1024 + kv_rd0], qf[0], s[nb], 0, 0, 0);
        s[nb] = __builtin_amdgcn_mfma_f32_16x16x32_f16(
            *(half8*)&Kb[nb * 1024 + kv_rd1], qf[1], s[nb], 0, 0, 0);
      }

      // ---- online softmax max (triple-nested for v_max3 fusion) ----
      float c0 = fmaxf(fmaxf(s[0][0], s[0][1]), s[0][2]);
      float c1 = fmaxf(fmaxf(s[0][3], s[1][0]), s[1][1]);
      float c2 = fmaxf(fmaxf(s[1][2], s[1][3]), s[2][0]);
      float c3 = fmaxf(fmaxf(s[2][1], s[2][2]), s[2][3]);
      float c4 = fmaxf(fmaxf(s[3][0], s[3][1]), s[3][2]);
      float cm = fmaxf(fmaxf(fmaxf(c0, c1), c2), fmaxf(fmaxf(c3, c4), s[3][3]));
      {
        int i = __builtin_amdgcn_ds_swizzle(__float_as_int(cm), 0x401F);  // xor 16
        cm = fmaxf(cm, __int_as_float(i));
        cm = fmaxf(cm, __shfl_xor(cm, 32));
      }
      // T13 exact: skip rescale when max didn't grow for any lane of the wave.
      if (!__all(cm <= m)) {
        float mn = fmaxf(m, cm);
        float al = exp2f(m - mn);
        l *= al;
#pragma unroll
        for (int nb = 0; nb < 4; nb++)
#pragma unroll
          for (int r = 0; r < 4; r++) o[nb][r] *= al;
        m = mn;
      }

      // ---- P = exp2(S + add), pack to f16 via pkrtz ----
      const float add = capped ? (((relh >= 106) ? tb_pos : tb_neg) - m) : (-m);
      float lsum = 0.0f;
      halfx4 pvb[4];   // PV B-frags: pvb[kt][j] = p(key = kt*16 + quad*4 + j)
#pragma unroll
      for (int nb = 0; nb < 4; nb++) {
        float p0 = exp2f(s[nb][0] + add);
        float p1 = exp2f(s[nb][1] + add);
        float p2 = exp2f(s[nb][2] + add);
        float p3 = exp2f(s[nb][3] + add);
        lsum += (p0 + p1) + (p2 + p3);
        fp16x2 a01 = __builtin_amdgcn_cvt_pkrtz(p0, p1);
        fp16x2 a23 = __builtin_amdgcn_cvt_pkrtz(p2, p3);
        fp16x4 a = __builtin_shufflevector(a01, a23, 0, 1, 2, 3);
        pvb[nb] = __builtin_bit_cast(halfx4, a);
      }
      l += lsum;   // per-lane partial; cross-quad reduce deferred to epilogue

      // ---- O^T += V^T P^T : 16 x mfma_16x16x16, A = Vt b64 frags ----
#pragma unroll
      for (int nb = 0; nb < 4; nb++) {
        const int vrow = (nb * 16 + l15);
        const int vsw = vrow & 7;
#pragma unroll
        for (int kt = 0; kt < 4; kt++) {
          halfx4 vf = *(halfx4*)&Vb[vrow * 64 + ((kt * 2 + q2h) ^ vsw) * 8 + q2l];
          o[nb] = __builtin_amdgcn_mfma_f32_16x16x16f16(vf, pvb[kt], o[nb], 0, 0, 0);
        }
      }
    }
  }

  // ---- epilogue: reduce l across quads, divide, write X fp16 directly ----
  {
    int i = __builtin_amdgcn_ds_swizzle(__float_as_int(l), 0x401F);   // xor 16
    l += __int_as_float(i);
    l += __shfl_xor(l, 32);
    const float inv = 1.0f / l;
    const int b = bh >> 4;
    half_t* xp = X + (size_t)(b * S_LEN + q0w + l15) * DMODEL + h * DKV;
#pragma unroll
    for (int nb = 0; nb < 4; nb++) {
      halfx4 hv;
#pragma unroll
      for (int r = 0; r < 4; r++) hv[r] = (half_t)(o[nb][r] * inv);
      *(halfx4*)(xp + nb * 16 + quad * 4) = hv;
    }
  }
}

// ---------------------------------------------------------------------------
// kernel_launch
// ws layout (halves): Ah 4M (reused as Vt) | Wqt 3M | Wot 1M | Qh 4M | Kh 4M |
//   Vh 4M | Xh 4M   (~48 MB)
// ---------------------------------------------------------------------------
extern "C" void kernel_launch(void* const* d_in, const int* in_sizes, int n_in,
                              void* d_out, int out_size, void* d_ws, size_t ws_size,
                              hipStream_t stream) {
  const float* hidden = (const float*)d_in[0];
  const float* w_qkv = (const float*)d_in[1];
  const float* w_o = (const float*)d_in[2];
  const float* table = (const float*)d_in[3];

  float* attn_out = (float*)d_out;
  float* bias_out = (float*)d_out + 4194304;

  half_t* Ah  = (half_t*)d_ws;     // hidden fp16; reused as Vt after QKV GEMM
  half_t* Wqt = Ah + 4194304;      // [3072][1024]
  half_t* Wot = Wqt + 3145728;     // [1024][1024]
  half_t* Qh  = Wot + 1048576;     // [b,h,s,d], pre-scaled by log2e
  half_t* Kh  = Qh + 4194304;      // [b,h,s,d]
  half_t* Vh  = Kh + 4194304;      // [b,h,s,d]
  half_t* Xh  = Vh + 4194304;      // [4096][1024]
  half_t* Vth = Ah;                // [b,h,d,s] (aliases Ah; Ah dead by then)

  // fused prep: bias rows + cast + both weight transposes (one dispatch)
  prep_all<<<40960, 256, 0, stream>>>(hidden, w_qkv, w_o, table,
                                      Ah, Wqt, Wot, bias_out);

  // QKV projection (fp16 MFMA; Q epilogue pre-scales by log2e)
  hgemm128<1><<<dim3(3072 / 128, 4096 / 128), 256, 0, stream>>>(
      Ah, Wqt, nullptr, Qh, Kh, Vh, 4096, 3072, 1024);

  // V -> Vt transpose (Ah is dead now; Vt aliases it)
  vtrans<<<dim3(S_LEN / 64, BATCH * NH), 256, 0, stream>>>(Vh, Vth);

  // fused fp16 MFMA flash attention -> Xh fp16
  attn_fused<<<dim3(S_LEN / 128, BATCH * NH), 512, 0, stream>>>(
      Qh, Kh, Vth, table, Xh);

  // output projection -> d_out fp32
  hgemm128<0><<<dim3(1024 / 128, 4096 / 128), 256, 0, stream>>>(
      Xh, Wot, attn_out, nullptr, nullptr, nullptr, 4096, 1024, 1024);
}

// Round 6
// 457.822 us; speedup vs baseline: 1.0867x; 1.0244x over previous
//
#include <hip/hip_runtime.h>
#include <hip/hip_bf16.h>
#include <cstdint>
#include <cstddef>

// Problem constants (T5 self-attention, B=2, S=2048, H=16, D=64, d_model=1024)
#define S_LEN 2048
#define NH 16
#define DKV 64
#define BATCH 2
#define DMODEL 1024
#define LOG2E 1.4426950408889634f

typedef _Float16 half_t;
typedef __attribute__((ext_vector_type(2))) __fp16 fp16x2;    // cvt_pkrtz result type
typedef __attribute__((ext_vector_type(4))) __fp16 fp16x4;
typedef __attribute__((ext_vector_type(4))) _Float16 halfx4;  // 8 B (also 16x16x16 A/B frag)
typedef __attribute__((ext_vector_type(8))) _Float16 half8;   // 16x16x32 A/B frag (4 VGPRs)
typedef __attribute__((ext_vector_type(4))) float floatx4;    // MFMA C/D frag / 16B store

// async global->LDS, 16 B per lane; LDS dest = wave-uniform base + lane*16
__device__ __forceinline__ void load_lds16(const half_t* g, half_t* l) {
  __builtin_amdgcn_global_load_lds((const __attribute__((address_space(1))) void*)g,
                                   (__attribute__((address_space(3))) void*)l, 16, 0, 0);
}

// ---------------------------------------------------------------------------
// T5 relative-position bucket — EXACT integer thresholds (ceil(8*16^(n/8))),
// verified to agree with the fp32 reference at every integer delta.
// Handles ALL deltas (caps at bucket 15/31 for |delta| >= 91).
// ---------------------------------------------------------------------------
__device__ __forceinline__ int t5_bucket(int delta) {
  int base = (delta > 0) ? 16 : 0;
  int a = delta < 0 ? -delta : delta;
  int n;
  if (a < 8)       n = a;
  else if (a < 12) n = 8;
  else if (a < 16) n = 9;
  else if (a < 23) n = 10;
  else if (a < 32) n = 11;
  else if (a < 46) n = 12;
  else if (a < 64) n = 13;
  else if (a < 91) n = 14;
  else             n = 15;
  return base + n;
}

// ---------------------------------------------------------------------------
// FUSED prep: ONE dispatch covering
//   blocks [0, 32768)        : position_bias rows (268 MB nontemporal write)
//   blocks [32768, 36864)    : hidden fp32 -> fp16 flat cast
//   blocks [36864, 39936)    : w_qkv fp32 [1024][3072] -> fp16 [3072][1024]
//   blocks [39936, 40960)    : w_o   fp32 [1024][1024] -> fp16 [1024][1024]^T
// ---------------------------------------------------------------------------
__global__ __launch_bounds__(256) void prep_all(const float* __restrict__ hidden,
                                                const float* __restrict__ w_qkv,
                                                const float* __restrict__ w_o,
                                                const float* __restrict__ table,
                                                half_t* __restrict__ Ah,
                                                half_t* __restrict__ Wqt,
                                                half_t* __restrict__ Wot,
                                                float* __restrict__ bias_out) {
  __shared__ float smem[32 * 33];
  const int id = blockIdx.x;
  const int tid = threadIdx.x;

  if (id < 32768) {
    // ---- position_bias row: out[(h*S+q)*S + k] = table[bucket(k-q)*NH + h]
    const int h = id >> 11;
    const int q = id & (S_LEN - 1);
    if (tid < 32) smem[tid] = table[tid * NH + h];
    __syncthreads();
    float* dst = bias_out + (size_t)id * S_LEN;
    const int k0 = tid * 4;
#pragma unroll
    for (int hf = 0; hf < 2; hf++) {
      int k = k0 + hf * 1024;
      floatx4 v;
      v[0] = smem[t5_bucket((k + 0) - q)];
      v[1] = smem[t5_bucket((k + 1) - q)];
      v[2] = smem[t5_bucket((k + 2) - q)];
      v[3] = smem[t5_bucket((k + 3) - q)];
      __builtin_nontemporal_store(v, (floatx4*)(dst + k));
    }
  } else if (id < 36864) {
    // ---- fp32 -> fp16 flat cast (hidden_states)
    const int i = (id - 32768) * 256 + tid;
    float4 v = ((const float4*)hidden)[i];
    halfx4 hv;
    hv[0] = (half_t)v.x; hv[1] = (half_t)v.y; hv[2] = (half_t)v.z; hv[3] = (half_t)v.w;
    ((halfx4*)Ah)[i] = hv;
  } else {
    // ---- fp32 [R][C] -> fp16 [C][R] transpose+cast (weights), 32x32 tile
    const float* in;
    half_t* out;
    int R, C, bx, by;
    if (id < 39936) {
      int t = id - 36864; bx = t % 96; by = t / 96;
      in = w_qkv; out = Wqt; R = 1024; C = 3072;
    } else {
      int t = id - 39936; bx = t & 31; by = t >> 5;
      in = w_o; out = Wot; R = 1024; C = 1024;
    }
    float (*t33)[33] = (float(*)[33])smem;
    const int lr = tid >> 3;
    const int lc = (tid & 7) * 4;
    const int r0 = by * 32, c0 = bx * 32;
    float4 v = *(const float4*)(in + (size_t)(r0 + lr) * C + c0 + lc);
    t33[lr][lc + 0] = v.x; t33[lr][lc + 1] = v.y;
    t33[lr][lc + 2] = v.z; t33[lr][lc + 3] = v.w;
    __syncthreads();
    halfx4 hv;
#pragma unroll
    for (int u = 0; u < 4; u++) hv[u] = (half_t)t33[lc + u][lr];
    *(halfx4*)(out + (size_t)(c0 + lr) * R + r0 + lc) = hv;
  }
}

// ---------------------------------------------------------------------------
// fp16 MFMA GEMM: C[M,N] = A[M,K] @ Bt[N,K]^T. 128x128 tile, BK=64, 256 thr
// (4 waves, 2x2), 4x4 mfma_f32_16x16x32_f16 frags per wave.
// SWAPPED operands (mfma(bf, af)): C transposed -> each lane holds 4
// CONSECUTIVE columns -> vectorized float4 / halfx4 epilogue stores.
// MODE 0: fp32 float4 store to C.
// MODE 1: QKV scatter -> Q,K fp16 [b,h,s,d] (Q PRE-SCALED by log2(e));
//         V written DIRECTLY TRANSPOSED to [b,h,d,s] (vtrans kernel fused
//         away; Vo must NOT alias A).
// ---------------------------------------------------------------------------
template <int MODE>
__global__ __launch_bounds__(256) void hgemm128(const half_t* __restrict__ A,
                                                const half_t* __restrict__ Bt,
                                                float* __restrict__ C,
                                                half_t* __restrict__ Qo,
                                                half_t* __restrict__ Ko,
                                                half_t* __restrict__ Vo,
                                                int M, int N, int K) {
  __shared__ half_t Asl[8 * 1024];   // 8 row-blocks x (16 rows x 64 k), lane-linear panels
  __shared__ half_t Bsl[8 * 1024];

  const int tid = threadIdx.x;
  const int w = tid >> 6;
  const int lane = tid & 63;
  const int l15 = lane & 15;
  const int quad = lane >> 4;
  const int wm = w >> 1, wn = w & 1;
  const int m0 = blockIdx.y * 128;
  const int n0 = blockIdx.x * 128;

  floatx4 acc[4][4];
#pragma unroll
  for (int i = 0; i < 4; i++)
#pragma unroll
    for (int j = 0; j < 4; j++) acc[i][j] = (floatx4){0.f, 0.f, 0.f, 0.f};

  const half_t* ga0 = A + (size_t)(m0 + (2 * w + 0) * 16 + l15) * K + quad * 8;
  const half_t* ga1 = A + (size_t)(m0 + (2 * w + 1) * 16 + l15) * K + quad * 8;
  const half_t* gb0 = Bt + (size_t)(n0 + (2 * w + 0) * 16 + l15) * K + quad * 8;
  const half_t* gb1 = Bt + (size_t)(n0 + (2 * w + 1) * 16 + l15) * K + quad * 8;
  half_t* la0 = &Asl[(2 * w + 0) * 1024];
  half_t* la1 = &Asl[(2 * w + 1) * 1024];
  half_t* lb0 = &Bsl[(2 * w + 0) * 1024];
  half_t* lb1 = &Bsl[(2 * w + 1) * 1024];

  for (int k0 = 0; k0 < K; k0 += 64) {
    __syncthreads();
    load_lds16(ga0 + k0,      la0);
    load_lds16(ga0 + k0 + 32, la0 + 512);
    load_lds16(ga1 + k0,      la1);
    load_lds16(ga1 + k0 + 32, la1 + 512);
    load_lds16(gb0 + k0,      lb0);
    load_lds16(gb0 + k0 + 32, lb0 + 512);
    load_lds16(gb1 + k0,      lb1);
    load_lds16(gb1 + k0 + 32, lb1 + 512);
    __syncthreads();

#pragma unroll
    for (int ks = 0; ks < 2; ks++) {
      half8 af[4], bf[4];
#pragma unroll
      for (int i = 0; i < 4; i++)
        af[i] = *(half8*)&Asl[(wm * 4 + i) * 1024 + ks * 512 + lane * 8];
#pragma unroll
      for (int j = 0; j < 4; j++)
        bf[j] = *(half8*)&Bsl[(wn * 4 + j) * 1024 + ks * 512 + lane * 8];
#pragma unroll
      for (int i = 0; i < 4; i++)
#pragma unroll
        for (int j = 0; j < 4; j++)
          acc[i][j] = __builtin_amdgcn_mfma_f32_16x16x32_f16(bf[j], af[i], acc[i][j], 0, 0, 0);
    }
  }

  // transposed C layout: lane holds C[row = rowbase+i*16+l15][col = colbase+j*16+quad*4 + r]
  const int rowbase = m0 + wm * 64;
  const int colbase = n0 + wn * 64;
  if (MODE == 0) {
#pragma unroll
    for (int i = 0; i < 4; i++)
#pragma unroll
      for (int j = 0; j < 4; j++)
        *(floatx4*)&C[(size_t)(rowbase + i * 16 + l15) * N + colbase + j * 16 + quad * 4] =
            acc[i][j];
  } else {
    const int which = colbase >> 10;            // 0=q,1=k,2=v (uniform per wave)
    const int h = (colbase & 1023) >> 6;        // uniform per wave
    const int b = rowbase >> 11;
    const int s0 = rowbase & (S_LEN - 1);
    if (which == 2) {
      // V: write directly transposed [b,h,d,s]; d = j*16 + quad*4 + r
      half_t* vbase = Vo + (size_t)(b * NH + h) * DKV * S_LEN;
#pragma unroll
      for (int i = 0; i < 4; i++)
#pragma unroll
        for (int j = 0; j < 4; j++)
#pragma unroll
          for (int r = 0; r < 4; r++)
            vbase[(size_t)(j * 16 + quad * 4 + r) * S_LEN + s0 + i * 16 + l15] =
                (half_t)acc[i][j][r];
    } else {
      const float scale = (which == 0) ? LOG2E : 1.0f;   // Q pre-scaled for exp2
      half_t* base = ((which == 0) ? Qo : Ko) + (size_t)(b * NH + h) * S_LEN * DKV;
#pragma unroll
      for (int i = 0; i < 4; i++)
#pragma unroll
        for (int j = 0; j < 4; j++) {
          halfx4 hv;
#pragma unroll
          for (int r = 0; r < 4; r++) hv[r] = (half_t)(acc[i][j][r] * scale);
          *(halfx4*)&base[(size_t)(s0 + i * 16 + l15) * DKV + j * 16 + quad * 4] = hv;
        }
    }
  }
}

// ---------------------------------------------------------------------------
// fp16 MFMA flash attention, 8 waves / 512 threads, 128 q/block.
//  - 128 keys staged per barrier pair (two 64-key buffers, identical layout)
//    -> 16 barrier pairs, deep T14 prefetch;
//  - bias folded into MFMA C-in via 4-phase float4-aligned table;
//  - max-reduce shaped for v_max3; P f32->f16 via v_cvt_pkrtz;
//  - T13 exact rescale skip; per-lane partial l (reduced in epilogue).
// ---------------------------------------------------------------------------
__global__ __launch_bounds__(512) void attn_fused(const half_t* __restrict__ Q,
                                                  const half_t* __restrict__ K,
                                                  const half_t* __restrict__ Vt,
                                                  const float* __restrict__ table,
                                                  half_t* __restrict__ X) {
  __shared__ half_t Ks[2 * 64 * 64];    // two [key][d] buffers, swizzled
  __shared__ half_t Vts[2 * 64 * 64];   // two [d][key] buffers, swizzled
  __shared__ float tb[32];
  __shared__ floatx4 badd4[352];        // 4 phase-copies x 88 float4 of
                                        // log2e*bias by (delta+168), aligned

  const int tid = threadIdx.x;
  const int w = tid >> 6;           // 0..7
  const int lane = tid & 63;
  const int l15 = lane & 15;
  const int quad = lane >> 4;
  const int bh = blockIdx.y;
  const int h = bh & (NH - 1);
  const int q0w = blockIdx.x * 128 + w * 16;

  if (tid < 32) tb[tid] = table[tid * NH + h] * LOG2E;
  __syncthreads();
  if (tid < 352) {
    const int p = tid / 88, t = tid - p * 88;
    floatx4 v;
#pragma unroll
    for (int e = 0; e < 4; e++) {
      int lin = p + 4 * t + e;
      if (lin > 343) lin = 343;
      v[e] = tb[t5_bucket(lin - 168)];
    }
    badd4[tid] = v;    // first consumer is after the loop's double barrier
  }
  const float tb_neg = tb[15], tb_pos = tb[31];   // capped-region biases (scaled)

  // Q B-fragments: B[k=quad*8+j][n=l15] = Q[q0w+l15][...]
  half8 qf[2];
#pragma unroll
  for (int ks = 0; ks < 2; ks++)
    qf[ks] = *(const half8*)(Q + ((size_t)bh * S_LEN + q0w + l15) * DKV +
                             ks * 32 + quad * 8);

  // O^T accumulators: o[nb] holds O[q=l15][d = nb*16 + quad*4 + r]
  floatx4 o[4];
#pragma unroll
  for (int nb = 0; nb < 4; nb++) o[nb] = (floatx4){0.f, 0.f, 0.f, 0.f};
  float m = -1e30f, l = 0.0f;       // l is PER-LANE PARTIAL (this quad's keys)

  // staging: 512 thr x 2x(16B K + 16B V); row jr = tid>>3, unit u = tid&7
  const int jr = tid >> 3;
  const int u = tid & 7;
  const int swu = (u ^ (jr & 7)) * 8;
  // S^T A-frag (K rows): addr = key*64 + ((ks*4+quad)^(key&7))*8, key=nb*16+l15
  const int kv_rd0 = l15 * 64 + ((0 * 4 + quad) ^ (l15 & 7)) * 8;
  const int kv_rd1 = l15 * 64 + ((1 * 4 + quad) ^ (l15 & 7)) * 8;
  // PV A-frag (Vt rows, b64): unit = kt*2 + (quad>>1), half-offset (quad&1)*4
  const int q2h = quad >> 1, q2l = (quad & 1) * 4;

  const half_t* Kg = K + ((size_t)bh * S_LEN + jr) * DKV + u * 8;
  const half_t* Vg = Vt + ((size_t)bh * DKV + jr) * S_LEN + u * 8;
  int rel = -q0w;   // kc - q0w, wave-uniform

  // T14: tile-pair 0 K/V prefetched into regs before the loop
  half8 kreg0 = *(const half8*)Kg;
  half8 kreg1 = *(const half8*)(Kg + 64 * DKV);
  half8 vreg0 = *(const half8*)Vg;
  half8 vreg1 = *(const half8*)(Vg + 64);

  for (int it = 0; it < 16; it++, rel += 128) {
    __syncthreads();                     // prev tiles' LDS reads done
    *(half8*)&Ks[jr * 64 + swu] = kreg0;
    *(half8*)&Ks[4096 + jr * 64 + swu] = kreg1;
    *(half8*)&Vts[jr * 64 + swu] = vreg0;
    *(half8*)&Vts[4096 + jr * 64 + swu] = vreg1;
    __syncthreads();
    if (it < 15) {                       // issue next pair's loads EARLY
      Kg += 128 * DKV;
      Vg += 128;
      kreg0 = *(const half8*)Kg;
      kreg1 = *(const half8*)(Kg + 64 * DKV);
      vreg0 = *(const half8*)Vg;
      vreg1 = *(const half8*)(Vg + 64);
    }

#pragma unroll
    for (int hb = 0; hb < 2; hb++) {
      const int relh = rel + hb * 64;
      const half_t* Kb = &Ks[hb * 4096];
      const half_t* Vb = &Vts[hb * 4096];

      // ---- S^T = K Q'^T (+bias in C-in for interior tiles) ----
      const bool capped = (relh >= 106 || relh <= -154);
      floatx4 s[4];
      if (capped) {
#pragma unroll
        for (int nb = 0; nb < 4; nb++) s[nb] = (floatx4){0.f, 0.f, 0.f, 0.f};
      } else {
        const int db = relh + quad * 4 - l15 + 168;   // in [9, 276]
        const int ph = db & 3;
        const int bb = db >> 2;
#pragma unroll
        for (int nb = 0; nb < 4; nb++) s[nb] = badd4[ph * 88 + bb + nb * 4];
      }
#pragma unroll
      for (int nb = 0; nb < 4; nb++) {
        s[nb] = __builtin_amdgcn_mfma_f32_16x16x32_f16(
            *(half8*)&Kb[nb * 1024 + kv_rd0], qf[0], s[nb], 0, 0, 0);
        s[nb] = __builtin_amdgcn_mfma_f32_16x16x32_f16(
            *(half8*)&Kb[nb * 1024 + kv_rd1], qf[1], s[nb], 0, 0, 0);
      }

      // ---- online softmax max (triple-nested for v_max3 fusion) ----
      float c0 = fmaxf(fmaxf(s[0][0], s[0][1]), s[0][2]);
      float c1 = fmaxf(fmaxf(s[0][3], s[1][0]), s[1][1]);
      float c2 = fmaxf(fmaxf(s[1][2], s[1][3]), s[2][0]);
      float c3 = fmaxf(fmaxf(s[2][1], s[2][2]), s[2][3]);
      float c4 = fmaxf(fmaxf(s[3][0], s[3][1]), s[3][2]);
      float cm = fmaxf(fmaxf(fmaxf(c0, c1), c2), fmaxf(fmaxf(c3, c4), s[3][3]));
      {
        int i = __builtin_amdgcn_ds_swizzle(__float_as_int(cm), 0x401F);  // xor 16
        cm = fmaxf(cm, __int_as_float(i));
        cm = fmaxf(cm, __shfl_xor(cm, 32));
      }
      // T13 exact: skip rescale when max didn't grow for any lane of the wave.
      if (!__all(cm <= m)) {
        float mn = fmaxf(m, cm);
        float al = exp2f(m - mn);
        l *= al;
#pragma unroll
        for (int nb = 0; nb < 4; nb++)
#pragma unroll
          for (int r = 0; r < 4; r++) o[nb][r] *= al;
        m = mn;
      }

      // ---- P = exp2(S + add), pack to f16 via pkrtz ----
      const float add = capped ? (((relh >= 106) ? tb_pos : tb_neg) - m) : (-m);
      float lsum = 0.0f;
      halfx4 pvb[4];   // PV B-frags: pvb[kt][j] = p(key = kt*16 + quad*4 + j)
#pragma unroll
      for (int nb = 0; nb < 4; nb++) {
        float p0 = exp2f(s[nb][0] + add);
        float p1 = exp2f(s[nb][1] + add);
        float p2 = exp2f(s[nb][2] + add);
        float p3 = exp2f(s[nb][3] + add);
        lsum += (p0 + p1) + (p2 + p3);
        fp16x2 a01 = __builtin_amdgcn_cvt_pkrtz(p0, p1);
        fp16x2 a23 = __builtin_amdgcn_cvt_pkrtz(p2, p3);
        fp16x4 a = __builtin_shufflevector(a01, a23, 0, 1, 2, 3);
        pvb[nb] = __builtin_bit_cast(halfx4, a);
      }
      l += lsum;   // per-lane partial; cross-quad reduce deferred to epilogue

      // ---- O^T += V^T P^T : 16 x mfma_16x16x16, A = Vt b64 frags ----
#pragma unroll
      for (int nb = 0; nb < 4; nb++) {
        const int vrow = (nb * 16 + l15);
        const int vsw = vrow & 7;
#pragma unroll
        for (int kt = 0; kt < 4; kt++) {
          halfx4 vf = *(halfx4*)&Vb[vrow * 64 + ((kt * 2 + q2h) ^ vsw) * 8 + q2l];
          o[nb] = __builtin_amdgcn_mfma_f32_16x16x16f16(vf, pvb[kt], o[nb], 0, 0, 0);
        }
      }
    }
  }

  // ---- epilogue: reduce l across quads, divide, write X fp16 directly ----
  {
    int i = __builtin_amdgcn_ds_swizzle(__float_as_int(l), 0x401F);   // xor 16
    l += __int_as_float(i);
    l += __shfl_xor(l, 32);
    const float inv = 1.0f / l;
    const int b = bh >> 4;
    half_t* xp = X + (size_t)(b * S_LEN + q0w + l15) * DMODEL + h * DKV;
#pragma unroll
    for (int nb = 0; nb < 4; nb++) {
      halfx4 hv;
#pragma unroll
      for (int r = 0; r < 4; r++) hv[r] = (half_t)(o[nb][r] * inv);
      *(halfx4*)(xp + nb * 16 + quad * 4) = hv;
    }
  }
}

// ---------------------------------------------------------------------------
// kernel_launch
// ws layout (halves): Ah 4M | Wqt 3M | Wot 1M | Qh 4M | Kh 4M | Vth 4M |
//   Xh 4M   (~48 MB). V is written TRANSPOSED by the QKV GEMM (no vtrans).
// ---------------------------------------------------------------------------
extern "C" void kernel_launch(void* const* d_in, const int* in_sizes, int n_in,
                              void* d_out, int out_size, void* d_ws, size_t ws_size,
                              hipStream_t stream) {
  const float* hidden = (const float*)d_in[0];
  const float* w_qkv = (const float*)d_in[1];
  const float* w_o = (const float*)d_in[2];
  const float* table = (const float*)d_in[3];

  float* attn_out = (float*)d_out;
  float* bias_out = (float*)d_out + 4194304;

  half_t* Ah  = (half_t*)d_ws;     // hidden fp16
  half_t* Wqt = Ah + 4194304;      // [3072][1024]
  half_t* Wot = Wqt + 3145728;     // [1024][1024]
  half_t* Qh  = Wot + 1048576;     // [b,h,s,d], pre-scaled by log2e
  half_t* Kh  = Qh + 4194304;      // [b,h,s,d]
  half_t* Vth = Kh + 4194304;      // [b,h,d,s]  (written directly by QKV GEMM)
  half_t* Xh  = Vth + 4194304;     // [4096][1024]

  // fused prep: bias rows + cast + both weight transposes (one dispatch)
  prep_all<<<40960, 256, 0, stream>>>(hidden, w_qkv, w_o, table,
                                      Ah, Wqt, Wot, bias_out);

  // QKV projection (fp16 MFMA; Q pre-scaled by log2e; V written transposed)
  hgemm128<1><<<dim3(3072 / 128, 4096 / 128), 256, 0, stream>>>(
      Ah, Wqt, nullptr, Qh, Kh, Vth, 4096, 3072, 1024);

  // fused fp16 MFMA flash attention -> Xh fp16
  attn_fused<<<dim3(S_LEN / 128, BATCH * NH), 512, 0, stream>>>(
      Qh, Kh, Vth, table, Xh);

  // output projection -> d_out fp32
  hgemm128<0><<<dim3(1024 / 128, 4096 / 128), 256, 0, stream>>>(
      Xh, Wot, attn_out, nullptr, nullptr, nullptr, 4096, 1024, 1024);
}